// Round 8
// baseline (476.956 us; speedup 1.0000x reference)
//
#include <hip/hip_runtime.h>
#include <hip/hip_bf16.h>

// ---------------------------------------------------------------------------
// globalAttention: b=16 t=7 c=64 h=w=64, P=8  ->  112 frames, S=448, D=4096
//   1) prep_w x2      : wv,wc fp32 [co][ci][3][3] -> bf16 Wt[r][co][ci]
//   2) conv_qk_unfold3: depthwise 3x3 conv (q,k); x staged via LDS (coalesced
//                       reads), 1KB contiguous wave stores
//   3) conv_mfma3<V>  : dense conv v, MFMA implicit GEMM; weights read from
//                       L2 into register ping-pong (no wl LDS, no K-loop
//                       barriers); xs-only LDS 50.7KB -> 3 blocks/CU (r7 lever)
//   4) gemm_qk_mfma   : ATTN = (1/64) Q K^T   (bf16 MFMA, fp32 out)
//   5) softmax_rows   : row softmax -> bf16 P  (P aliases Kb)
//   6) gemm_pv_mfma   : FEAT[f][c][y][x] bf16 = P @ V   (V transposed in LDS)
//   7) conv_mfma3<C>  : dense conv c + bias + residual -> d_out (float4 stores)
// Workspace: Qb[58.7M] Kb[58.7M] Vb[58.7M] ATTN[12.8M] Wt[144K]
// P(bf16) aliases Kb; FEAT(bf16) aliases Qb. Total ~189.5 MiB.
// ---------------------------------------------------------------------------

namespace {
constexpr int NFR = 112;
constexpr int T_  = 7;
constexpr int B_  = 16;
constexpr int C_  = 64;
constexpr int H_  = 64;
constexpr int W_  = 64;
constexpr int S_  = 448;
constexpr int D_  = 4096;
constexpr size_t QKV_E = (size_t)B_ * S_ * D_;
constexpr size_t ATTN_E = (size_t)B_ * S_ * S_;
}

typedef __attribute__((ext_vector_type(8))) short short8v;
typedef __attribute__((ext_vector_type(4))) float float4v;

__device__ __forceinline__ float bfu2f(unsigned short u) {
    union { unsigned int i; float f; } v; v.i = ((unsigned int)u) << 16; return v.f;
}
__device__ __forceinline__ unsigned short f2bf(float f) {
    __hip_bfloat16 h = __float2bfloat16(f);
    return *reinterpret_cast<unsigned short*>(&h);
}

// element (r, k) of a Rx64-short tile lives at byte r*128 + ((2k)^((r&7)<<4))
__device__ __forceinline__ short8v frag_ld(const char* ldsb, int r, int kByte) {
    return *(const short8v*)(ldsb + r * 128 + (kByte ^ ((r & 7) << 4)));
}

// stage 128 rows x 64 shorts from g (row stride ldg shorts) into swizzled LDS
template<int NTHR>
__device__ __forceinline__ void stage_tile(char* ldsb, const unsigned short* g,
                                           int ldg, int t) {
    #pragma unroll
    for (int i = 0; i < 1024 / NTHR; ++i) {
        int e = i * NTHR + t;
        int r = e >> 3, c8 = (e & 7) * 8;
        short8v v = *(const short8v*)(g + (size_t)r * ldg + c8);
        *(short8v*)(ldsb + r * 128 + ((c8 * 2) ^ ((r & 7) << 4))) = v;
    }
}

// stage V[u][d] tile (64 u x 128 d) TRANSPOSED into LDS as [d][u] swizzled
__device__ __forceinline__ void stage_vt(char* ldsb, const unsigned short* g, int t) {
    int d0 = (t & 15) * 8;
    int u0 = (t >> 4) * 4;
    short8v r0 = *(const short8v*)(g + (size_t)(u0 + 0) * D_ + d0);
    short8v r1 = *(const short8v*)(g + (size_t)(u0 + 1) * D_ + d0);
    short8v r2 = *(const short8v*)(g + (size_t)(u0 + 2) * D_ + d0);
    short8v r3 = *(const short8v*)(g + (size_t)(u0 + 3) * D_ + d0);
    #pragma unroll
    for (int j = 0; j < 8; ++j) {
        unsigned int lo = (unsigned short)r0[j] | (((unsigned int)(unsigned short)r1[j]) << 16);
        unsigned int hi = (unsigned short)r2[j] | (((unsigned int)(unsigned short)r3[j]) << 16);
        int d = d0 + j;
        int byte = d * 128 + (((unsigned)(u0 * 2)) ^ ((d & 7) << 4));
        *(uint2*)(ldsb + byte) = uint2{lo, hi};
    }
}

// ---------------- 1) weight transpose: [co][ci][3][3] f32 -> [r][co][ci] bf16
__global__ __launch_bounds__(256) void prep_w(const float* __restrict__ wsrc,
                                              __hip_bfloat16* __restrict__ wdst)
{
    int t = blockIdx.x * 256 + threadIdx.x;
    if (t >= 9 * 64 * 64) return;
    int r = t >> 12, co = (t >> 6) & 63, ci = t & 63;
    wdst[t] = __float2bfloat16(wsrc[(co * 64 + ci) * 9 + r]);
}

// ---------------- 2) depthwise conv q,k + unfold, LDS-staged x --------------
__global__ __launch_bounds__(256) void conv_qk_unfold3(
    const float* __restrict__ x,
    const float* __restrict__ wq, const float* __restrict__ bq,
    const float* __restrict__ wk, const float* __restrict__ bk,
    __hip_bfloat16* __restrict__ Q, __hip_bfloat16* __restrict__ K)
{
    __shared__ float xls[8][10][67];
    int py  = blockIdx.x;          // 0..7
    int oc8 = blockIdx.y;          // 0..7
    int f   = blockIdx.z;          // 0..111
    int t = threadIdx.x;
    int yb = py * 8 - 1;

    for (int e = t; e < 8 * 10 * 64; e += 256) {
        int col = e & 63;
        int row = (e >> 6) % 10;
        int ch  = e / 640;
        int y = yb + row;
        float v = 0.f;
        if ((unsigned)y < (unsigned)H_)
            v = x[(((size_t)f * C_ + oc8 * 8 + ch) * H_ + y) * W_ + col];
        xls[ch][row][col + 1] = v;
    }
    for (int e = t; e < 8 * 10 * 3; e += 256) {
        int which = e % 3;
        int row = (e / 3) % 10;
        int ch  = e / 30;
        xls[ch][row][which == 0 ? 0 : 64 + which] = 0.f;
    }
    __syncthreads();

    int w = t >> 6, lane = t & 63;
    int cg = lane >> 3, ky = lane & 7;
    int c  = oc8 * 8 + cg;
    float wqr[9], wkr[9];
    #pragma unroll
    for (int i = 0; i < 9; ++i) { wqr[i] = wq[c * 9 + i]; wkr[i] = wk[c * 9 + i]; }
    float bqv = bq[c], bkv = bk[c];
    int b = f / T_, tt = f % T_;
    unsigned short* Qp = (unsigned short*)Q;
    unsigned short* Kp = (unsigned short*)K;

    #pragma unroll
    for (int pi = 0; pi < 2; ++pi) {
        int px = w + pi * 4;
        int xb = px * 8;
        float acq[8], ack[8];
        #pragma unroll
        for (int j = 0; j < 8; ++j) { acq[j] = bqv; ack[j] = bkv; }
        #pragma unroll
        for (int dy = 0; dy < 3; ++dy) {
            const float* rp = &xls[cg][ky + dy][xb];   // cols xb-1 .. xb+8
            float r[10];
            #pragma unroll
            for (int j = 0; j < 10; ++j) r[j] = rp[j];
            float w0q = wqr[dy * 3], w1q = wqr[dy * 3 + 1], w2q = wqr[dy * 3 + 2];
            float w0k = wkr[dy * 3], w1k = wkr[dy * 3 + 1], w2k = wkr[dy * 3 + 2];
            #pragma unroll
            for (int j = 0; j < 8; ++j) {
                acq[j] += w0q * r[j] + w1q * r[j + 1] + w2q * r[j + 2];
                ack[j] += w0k * r[j] + w1k * r[j + 1] + w2k * r[j + 2];
            }
        }
        int s = tt * 64 + py * 8 + px;
        size_t off = ((size_t)b * S_ + s) * D_ + (size_t)c * 64 + ky * 8;
        unsigned short pq[8], pk[8];
        #pragma unroll
        for (int j = 0; j < 8; ++j) { pq[j] = f2bf(acq[j]); pk[j] = f2bf(ack[j]); }
        *(short8v*)(Qp + off) = *(const short8v*)pq;
        *(short8v*)(Kp + off) = *(const short8v*)pk;
    }
}

// ---------------- 3/7) dense 3x3 conv: implicit-GEMM MFMA, W from L2 --------
// Block: frame x 4-row band. 4 waves; wave w owns output row y0+w.
// Per wave: M=64 (x) x N=64 (co), K=576. A=x-frag (LDS), B=W-frag loaded
// DIRECTLY from global (L2-hot, 72KB) into a register ping-pong — no wl LDS,
// no barriers in the K-loop. LDS = xs only (50688B) -> 3 blocks/CU.
template<bool IS_V>
__global__ __launch_bounds__(256, 3) void conv_mfma3(
    const void* __restrict__ src,                 // IS_V: f32 x ; else bf16 FEAT
    const __hip_bfloat16* __restrict__ Wt,        // [9][64][64] bf16
    const float* __restrict__ bias,
    const float* __restrict__ xin,                // residual input (conv_c)
    void* __restrict__ dst)                       // IS_V: bf16 V ; else f32 out
{
    __shared__ char xs[6 * 66 * 128];             // 50688 B
    const int f    = blockIdx.y;
    const int band = blockIdx.x;                  // 0..15
    const int y0   = band * 4;
    const int tid  = threadIdx.x;
    const int lane = tid & 63;
    const int w    = tid >> 6;
    const int q    = lane >> 4;
    const int l15  = lane & 15;

    const unsigned short* Wg = (const unsigned short*)Wt;
    // per-lane base for weight fragments: row l15 (of 16-row group), col q*8
    const unsigned short* wbase = Wg + l15 * 64 + q * 8;

    short8v wf[2][8];
    // prefetch tap 0 fragments (hidden under xs staging)
    #pragma unroll
    for (int kc = 0; kc < 2; ++kc)
        #pragma unroll
        for (int nt = 0; nt < 4; ++nt)
            wf[0][kc * 4 + nt] = *(const short8v*)(wbase + nt * 16 * 64 + kc * 32);

    // ---- stage xs: input rows y0-1 .. y0+4
    for (int e = tid; e < 6 * 16 * 64; e += 256) {
        int x  = e & 63;
        int cg = (e >> 6) & 15;
        int r  = e >> 10;
        int y  = y0 - 1 + r;
        unsigned short p[4];
        if ((unsigned)y < (unsigned)H_) {
            #pragma unroll
            for (int j = 0; j < 4; ++j) {
                size_t gi = (((size_t)f * C_ + cg * 4 + j) * H_ + y) * W_ + x;
                if constexpr (IS_V) p[j] = f2bf(((const float*)src)[gi]);
                else                p[j] = ((const unsigned short*)src)[gi];
            }
        } else { p[0] = p[1] = p[2] = p[3] = 0; }
        int xp = x + 1;
        int byte = (r * 66 + xp) * 128 + ((cg * 8) ^ ((xp & 7) << 4));
        *(uint2*)(xs + byte) = *(uint2*)p;
    }
    for (int e = tid; e < 6 * 16 * 2; e += 256) {
        int side = e & 1;
        int cg   = (e >> 1) & 15;
        int r    = e >> 5;
        int xp   = side ? 65 : 0;
        int byte = (r * 66 + xp) * 128 + ((cg * 8) ^ ((xp & 7) << 4));
        *(uint2*)(xs + byte) = uint2{0u, 0u};
    }
    __syncthreads();

    float4v acc[4][4] = {};
    #pragma unroll
    for (int tap = 0; tap < 9; ++tap) {
        const int ky = tap / 3, kx = tap - ky * 3;
        // issue next tap's fragment loads before computing this tap
        if (tap + 1 < 9) {
            #pragma unroll
            for (int kc = 0; kc < 2; ++kc)
                #pragma unroll
                for (int nt = 0; nt < 4; ++nt)
                    wf[(tap + 1) & 1][kc * 4 + nt] =
                        *(const short8v*)(wbase + (tap + 1) * 4096 + nt * 16 * 64 + kc * 32);
        }
        const int ri = w + ky;                    // xs row slot for this wave
        #pragma unroll
        for (int kc = 0; kc < 2; ++kc) {
            int kB = kc * 64 + q * 16;
            #pragma unroll
            for (int xt = 0; xt < 4; ++xt) {
                int xp = xt * 16 + l15 + kx;
                short8v av = *(const short8v*)(xs + (ri * 66 + xp) * 128 +
                                               (kB ^ ((xp & 7) << 4)));
                #pragma unroll
                for (int nt = 0; nt < 4; ++nt)
                    acc[xt][nt] = __builtin_amdgcn_mfma_f32_16x16x32_bf16(
                        av, wf[tap & 1][kc * 4 + nt], acc[xt][nt], 0, 0, 0);
            }
        }
    }

    // ---- epilogue: D col(l15)=co, row(q*4+j)=x
    float bco[4];
    #pragma unroll
    for (int nt = 0; nt < 4; ++nt) bco[nt] = bias[nt * 16 + l15];
    const int bb = f / T_, tt = f % T_;
    const int R = y0 + w;
    #pragma unroll
    for (int xt = 0; xt < 4; ++xt) {
        #pragma unroll
        for (int nt = 0; nt < 4; ++nt) {
            int co = nt * 16 + l15;
            if constexpr (IS_V) {
                int s  = tt * 64 + (R >> 3) * 8 + xt * 2 + (q >> 1);
                int d0 = co * 64 + (R & 7) * 8 + (q & 1) * 4;
                unsigned short pk[4];
                #pragma unroll
                for (int j = 0; j < 4; ++j)
                    pk[j] = f2bf(acc[xt][nt][j] + bco[nt]);
                *(uint2*)((unsigned short*)dst + ((size_t)bb * S_ + s) * D_ + d0) =
                    *(const uint2*)pk;
            } else {
                size_t o = (((size_t)f * C_ + co) * H_ + R) * W_ + xt * 16 + q * 4;
                float4 rv = *(const float4*)(xin + o);
                float4 ov;
                ov.x = acc[xt][nt][0] + bco[nt] + rv.x;
                ov.y = acc[xt][nt][1] + bco[nt] + rv.y;
                ov.z = acc[xt][nt][2] + bco[nt] + rv.z;
                ov.w = acc[xt][nt][3] + bco[nt] + rv.w;
                *(float4*)((float*)dst + o) = ov;
            }
        }
    }
}

// ---------------- 4) ATTN = (1/64) Q K^T via MFMA ---------------------------
__global__ __launch_bounds__(512, 2) void gemm_qk_mfma(
    const __hip_bfloat16* __restrict__ Qg,
    const __hip_bfloat16* __restrict__ Kg,
    float* __restrict__ ATTN)
{
    __shared__ alignas(16) char lds[32768];
    char* ldsA = lds;
    char* ldsB = lds + 16384;
    int bid = blockIdx.x;
    int lb  = (bid & 7) * 32 + (bid >> 3);
    int bb  = lb >> 4;
    int m0  = ((lb >> 2) & 3) * 128;
    int n0  = (lb & 3) * 128;
    const unsigned short* Ag = (const unsigned short*)Qg + (size_t)bb * S_ * D_ + (size_t)m0 * D_;
    const unsigned short* Bg = (const unsigned short*)Kg + (size_t)bb * S_ * D_ + (size_t)n0 * D_;
    int t = threadIdx.x;
    int w = t >> 6, l = t & 63, q = l >> 4, l15 = l & 15;
    int wm = w >> 2, wn = w & 3;
    int r0 = t >> 3, c0 = (t & 7) * 8;
    int r1 = 64 + r0;
    short8v sA0, sA1, sB0, sB1;
    sA0 = *(const short8v*)(Ag + (size_t)r0 * D_ + c0);
    sA1 = *(const short8v*)(Ag + (size_t)r1 * D_ + c0);
    sB0 = *(const short8v*)(Bg + (size_t)r0 * D_ + c0);
    sB1 = *(const short8v*)(Bg + (size_t)r1 * D_ + c0);

    float4v acc[4][2] = {};
    int swz0 = (c0 * 2) ^ ((r0 & 7) << 4);
    for (int k0 = 0; k0 < D_; k0 += 64) {
        __syncthreads();
        *(short8v*)(ldsA + r0 * 128 + swz0) = sA0;
        *(short8v*)(ldsA + r1 * 128 + swz0) = sA1;
        *(short8v*)(ldsB + r0 * 128 + swz0) = sB0;
        *(short8v*)(ldsB + r1 * 128 + swz0) = sB1;
        if (k0 + 64 < D_) {
            int kn = k0 + 64;
            sA0 = *(const short8v*)(Ag + (size_t)r0 * D_ + kn + c0);
            sA1 = *(const short8v*)(Ag + (size_t)r1 * D_ + kn + c0);
            sB0 = *(const short8v*)(Bg + (size_t)r0 * D_ + kn + c0);
            sB1 = *(const short8v*)(Bg + (size_t)r1 * D_ + kn + c0);
        }
        __syncthreads();
        #pragma unroll
        for (int kc = 0; kc < 2; ++kc) {
            int kB = kc * 64 + q * 16;
            short8v a[4], b[2];
            #pragma unroll
            for (int mt = 0; mt < 4; ++mt) a[mt] = frag_ld(ldsA, wm * 64 + mt * 16 + l15, kB);
            #pragma unroll
            for (int nt = 0; nt < 2; ++nt) b[nt] = frag_ld(ldsB, wn * 32 + nt * 16 + l15, kB);
            #pragma unroll
            for (int mt = 0; mt < 4; ++mt)
                #pragma unroll
                for (int nt = 0; nt < 2; ++nt)
                    acc[mt][nt] = __builtin_amdgcn_mfma_f32_16x16x32_bf16(
                        a[mt], b[nt], acc[mt][nt], 0, 0, 0);
        }
    }
    const float scale = 1.0f / 64.0f;
    #pragma unroll
    for (int mt = 0; mt < 4; ++mt) {
        #pragma unroll
        for (int nt = 0; nt < 2; ++nt) {
            int u = n0 + wn * 32 + nt * 16 + l15;
            #pragma unroll
            for (int j = 0; j < 4; ++j) {
                int s = m0 + wm * 64 + mt * 16 + q * 4 + j;
                if (s < S_ && u < S_)
                    ATTN[((size_t)bb * S_ + s) * S_ + u] = acc[mt][nt][j] * scale;
            }
        }
    }
}

// ---------------- 5) row softmax -> bf16 P ----------------------------------
__global__ __launch_bounds__(64) void softmax_rows(const float* __restrict__ ATTN,
                                                   unsigned short* __restrict__ P)
{
    size_t row = blockIdx.x;
    const float* p = ATTN + row * S_;
    int lane = threadIdx.x;
    float vals[7];
    float m = -1e30f;
    #pragma unroll
    for (int i = 0; i < 7; ++i) { vals[i] = p[lane + i * 64]; m = fmaxf(m, vals[i]); }
    #pragma unroll
    for (int off = 32; off; off >>= 1) m = fmaxf(m, __shfl_xor(m, off));
    float sum = 0.f;
    #pragma unroll
    for (int i = 0; i < 7; ++i) { vals[i] = __expf(vals[i] - m); sum += vals[i]; }
    #pragma unroll
    for (int off = 32; off; off >>= 1) sum += __shfl_xor(sum, off);
    float inv = 1.f / sum;
    #pragma unroll
    for (int i = 0; i < 7; ++i) P[row * S_ + lane + i * 64] = f2bf(vals[i] * inv);
}

// ---------------- 6) FEAT = P @ V via MFMA (V transposed in LDS) ------------
__global__ __launch_bounds__(256, 2) void gemm_pv_mfma(
    const unsigned short* __restrict__ Pg,
    const __hip_bfloat16* __restrict__ Vg,
    __hip_bfloat16* __restrict__ FEAT)
{
    __shared__ alignas(16) char lds[32768];
    char* ldsA = lds;
    char* ldsB = lds + 16384;
    int bid = blockIdx.x;
    int lb  = (bid & 7) * 256 + (bid >> 3);
    int bb  = lb >> 7;
    int tl  = lb & 127;
    int m0  = (tl >> 5) * 128;
    int n0  = (tl & 31) * 128;
    const unsigned short* Ag = Pg + (size_t)bb * S_ * S_ + (size_t)m0 * S_;
    const unsigned short* Bg = (const unsigned short*)Vg + (size_t)bb * S_ * D_ + n0;
    int t = threadIdx.x;
    int w = t >> 6, l = t & 63, q = l >> 4, l15 = l & 15;
    int wm = w >> 1, wn = w & 1;
    float4v acc[4][4] = {};
    for (int k0 = 0; k0 < S_; k0 += 64) {
        __syncthreads();
        stage_tile<256>(ldsA, Ag + k0, S_, t);
        stage_vt(ldsB, Bg + (size_t)k0 * D_, t);
        __syncthreads();
        #pragma unroll
        for (int kc = 0; kc < 2; ++kc) {
            int kB = kc * 64 + q * 16;
            short8v a[4], b[4];
            #pragma unroll
            for (int mt = 0; mt < 4; ++mt) a[mt] = frag_ld(ldsA, wm * 64 + mt * 16 + l15, kB);
            #pragma unroll
            for (int nt = 0; nt < 4; ++nt) b[nt] = frag_ld(ldsB, wn * 64 + nt * 16 + l15, kB);
            #pragma unroll
            for (int mt = 0; mt < 4; ++mt)
                #pragma unroll
                for (int nt = 0; nt < 4; ++nt)
                    acc[mt][nt] = __builtin_amdgcn_mfma_f32_16x16x32_bf16(
                        a[mt], b[nt], acc[mt][nt], 0, 0, 0);
        }
    }
    #pragma unroll
    for (int mt = 0; mt < 4; ++mt) {
        #pragma unroll
        for (int j = 0; j < 4; ++j) {
            int s = m0 + wm * 64 + mt * 16 + q * 4 + j;
            if (s >= S_) continue;
            int f  = bb * T_ + (s >> 6);
            int l6 = s & 63;
            #pragma unroll
            for (int nt = 0; nt < 4; ++nt) {
                int d = n0 + wn * 64 + nt * 16 + l15;
                int c = d >> 6, r = d & 63;
                int y  = ((l6 >> 3) << 3) + (r >> 3);
                int xx = ((l6 & 7) << 3) + (r & 7);
                FEAT[(((size_t)f * C_ + c) * H_ + y) * W_ + xx] =
                    __float2bfloat16(acc[mt][nt][j]);
            }
        }
    }
}

// ---------------------------------------------------------------------------
extern "C" void kernel_launch(void* const* d_in, const int* in_sizes, int n_in,
                              void* d_out, int out_size, void* d_ws, size_t ws_size,
                              hipStream_t stream)
{
    const float* x  = (const float*)d_in[0];
    const float* wq = (const float*)d_in[1];
    const float* bq = (const float*)d_in[2];
    const float* wk = (const float*)d_in[3];
    const float* bk = (const float*)d_in[4];
    const float* wv = (const float*)d_in[5];
    const float* bv = (const float*)d_in[6];
    const float* wc = (const float*)d_in[7];
    const float* bc = (const float*)d_in[8];
    float* out = (float*)d_out;

    __hip_bfloat16* Qb = (__hip_bfloat16*)d_ws;
    __hip_bfloat16* Kb = Qb + QKV_E;
    __hip_bfloat16* Vb = Kb + QKV_E;
    float* ATTN = (float*)(Vb + QKV_E);
    __hip_bfloat16* Wt_v = (__hip_bfloat16*)(ATTN + ATTN_E);
    __hip_bfloat16* Wt_c = Wt_v + 9 * 64 * 64;
    unsigned short* Pb   = (unsigned short*)Kb;   // aliases Kb (dead after qk)
    __hip_bfloat16* FEAT = Qb;                    // aliases Qb (dead after qk)

    prep_w<<<144, 256, 0, stream>>>(wv, Wt_v);
    prep_w<<<144, 256, 0, stream>>>(wc, Wt_c);

    conv_qk_unfold3<<<dim3(8, 8, NFR), 256, 0, stream>>>(x, wq, bq, wk, bk, Qb, Kb);
    conv_mfma3<true><<<dim3(16, NFR), 256, 0, stream>>>(x, Wt_v, bv, nullptr, Vb);
    gemm_qk_mfma<<<256, 512, 0, stream>>>(Qb, Kb, ATTN);
    softmax_rows<<<B_ * S_, 64, 0, stream>>>(ATTN, Pb);
    gemm_pv_mfma<<<2048, 256, 0, stream>>>(Pb, Vb, FEAT);
    conv_mfma3<false><<<dim3(16, NFR), 256, 0, stream>>>(FEAT, Wt_c, bc, x, out);
}

// Round 9
// 397.498 us; speedup vs baseline: 1.1999x; 1.1999x over previous
//
#include <hip/hip_runtime.h>
#include <hip/hip_bf16.h>

// ---------------------------------------------------------------------------
// globalAttention: b=16 t=7 c=64 h=w=64, P=8  ->  112 frames, S=448, D=4096
//   1) prep_w2        : wv,wc fp32 [co][ci][3][3] -> bf16 Wt[r][co][ci] (fused)
//   2) conv_qk_unfold3: depthwise 3x3 conv (q,k); x staged via LDS
//   3) conv_mfma4<V>  : dense conv v, MFMA implicit GEMM; r6 compute + wl
//                       tap-level double-buffer (1 barrier/tap, stage latency
//                       hidden under MFMA; sched_barrier pins load issue)
//   4) gemm_qk_mfma   : ATTN = (1/64) Q K^T   (bf16 MFMA, fp32 out)
//   5) softmax_rows   : row softmax -> bf16 P  (P aliases Kb)
//   6) gemm_pv_mfma   : FEAT[f][c][y][x] bf16 = P @ V   (V transposed in LDS)
//   7) conv_mfma4<C>  : dense conv c + bias + residual -> d_out
// Workspace: Qb[58.7M] Kb[58.7M] Vb[58.7M] ATTN[12.8M] Wt[144K]
// P(bf16) aliases Kb; FEAT(bf16) aliases Qb. Total ~189.5 MiB.
// ---------------------------------------------------------------------------

namespace {
constexpr int NFR = 112;
constexpr int T_  = 7;
constexpr int B_  = 16;
constexpr int C_  = 64;
constexpr int H_  = 64;
constexpr int W_  = 64;
constexpr int S_  = 448;
constexpr int D_  = 4096;
constexpr size_t QKV_E = (size_t)B_ * S_ * D_;
constexpr size_t ATTN_E = (size_t)B_ * S_ * S_;
}

typedef __attribute__((ext_vector_type(8))) short short8v;
typedef __attribute__((ext_vector_type(4))) float float4v;

__device__ __forceinline__ float bfu2f(unsigned short u) {
    union { unsigned int i; float f; } v; v.i = ((unsigned int)u) << 16; return v.f;
}
__device__ __forceinline__ unsigned short f2bf(float f) {
    __hip_bfloat16 h = __float2bfloat16(f);
    return *reinterpret_cast<unsigned short*>(&h);
}

// element (r, k) of a Rx64-short tile lives at byte r*128 + ((2k)^((r&7)<<4))
__device__ __forceinline__ short8v frag_ld(const char* ldsb, int r, int kByte) {
    return *(const short8v*)(ldsb + r * 128 + (kByte ^ ((r & 7) << 4)));
}

// stage 128 rows x 64 shorts from g (row stride ldg shorts) into swizzled LDS
template<int NTHR>
__device__ __forceinline__ void stage_tile(char* ldsb, const unsigned short* g,
                                           int ldg, int t) {
    #pragma unroll
    for (int i = 0; i < 1024 / NTHR; ++i) {
        int e = i * NTHR + t;
        int r = e >> 3, c8 = (e & 7) * 8;
        short8v v = *(const short8v*)(g + (size_t)r * ldg + c8);
        *(short8v*)(ldsb + r * 128 + ((c8 * 2) ^ ((r & 7) << 4))) = v;
    }
}

// stage V[u][d] tile (64 u x 128 d) TRANSPOSED into LDS as [d][u] swizzled
__device__ __forceinline__ void stage_vt(char* ldsb, const unsigned short* g, int t) {
    int d0 = (t & 15) * 8;
    int u0 = (t >> 4) * 4;
    short8v r0 = *(const short8v*)(g + (size_t)(u0 + 0) * D_ + d0);
    short8v r1 = *(const short8v*)(g + (size_t)(u0 + 1) * D_ + d0);
    short8v r2 = *(const short8v*)(g + (size_t)(u0 + 2) * D_ + d0);
    short8v r3 = *(const short8v*)(g + (size_t)(u0 + 3) * D_ + d0);
    #pragma unroll
    for (int j = 0; j < 8; ++j) {
        unsigned int lo = (unsigned short)r0[j] | (((unsigned int)(unsigned short)r1[j]) << 16);
        unsigned int hi = (unsigned short)r2[j] | (((unsigned int)(unsigned short)r3[j]) << 16);
        int d = d0 + j;
        int byte = d * 128 + (((unsigned)(u0 * 2)) ^ ((d & 7) << 4));
        *(uint2*)(ldsb + byte) = uint2{lo, hi};
    }
}

// ---------------- 1) fused weight transpose (wv+wc) -------------------------
__global__ __launch_bounds__(256) void prep_w2(const float* __restrict__ wv,
                                               const float* __restrict__ wc,
                                               __hip_bfloat16* __restrict__ Wt_v,
                                               __hip_bfloat16* __restrict__ Wt_c)
{
    int t = blockIdx.x * 256 + threadIdx.x;          // 2*36864 = 73728
    if (t >= 2 * 36864) return;
    int which = t >= 36864;
    int i = t - which * 36864;
    const float* s = which ? wc : wv;
    __hip_bfloat16* d = which ? Wt_c : Wt_v;
    int r = i >> 12, co = (i >> 6) & 63, ci = i & 63;
    d[i] = __float2bfloat16(s[(co * 64 + ci) * 9 + r]);
}

// ---------------- 2) depthwise conv q,k + unfold, LDS-staged x --------------
__global__ __launch_bounds__(256) void conv_qk_unfold3(
    const float* __restrict__ x,
    const float* __restrict__ wq, const float* __restrict__ bq,
    const float* __restrict__ wk, const float* __restrict__ bk,
    __hip_bfloat16* __restrict__ Q, __hip_bfloat16* __restrict__ K)
{
    __shared__ float xls[8][10][67];
    int py  = blockIdx.x;          // 0..7
    int oc8 = blockIdx.y;          // 0..7
    int f   = blockIdx.z;          // 0..111
    int t = threadIdx.x;
    int yb = py * 8 - 1;

    for (int e = t; e < 8 * 10 * 64; e += 256) {
        int col = e & 63;
        int row = (e >> 6) % 10;
        int ch  = e / 640;
        int y = yb + row;
        float v = 0.f;
        if ((unsigned)y < (unsigned)H_)
            v = x[(((size_t)f * C_ + oc8 * 8 + ch) * H_ + y) * W_ + col];
        xls[ch][row][col + 1] = v;
    }
    for (int e = t; e < 8 * 10 * 3; e += 256) {
        int which = e % 3;
        int row = (e / 3) % 10;
        int ch  = e / 30;
        xls[ch][row][which == 0 ? 0 : 64 + which] = 0.f;
    }
    __syncthreads();

    int w = t >> 6, lane = t & 63;
    int cg = lane >> 3, ky = lane & 7;
    int c  = oc8 * 8 + cg;
    float wqr[9], wkr[9];
    #pragma unroll
    for (int i = 0; i < 9; ++i) { wqr[i] = wq[c * 9 + i]; wkr[i] = wk[c * 9 + i]; }
    float bqv = bq[c], bkv = bk[c];
    int b = f / T_, tt = f % T_;
    unsigned short* Qp = (unsigned short*)Q;
    unsigned short* Kp = (unsigned short*)K;

    #pragma unroll
    for (int pi = 0; pi < 2; ++pi) {
        int px = w + pi * 4;
        int xb = px * 8;
        float acq[8], ack[8];
        #pragma unroll
        for (int j = 0; j < 8; ++j) { acq[j] = bqv; ack[j] = bkv; }
        #pragma unroll
        for (int dy = 0; dy < 3; ++dy) {
            const float* rp = &xls[cg][ky + dy][xb];   // cols xb-1 .. xb+8
            float r[10];
            #pragma unroll
            for (int j = 0; j < 10; ++j) r[j] = rp[j];
            float w0q = wqr[dy * 3], w1q = wqr[dy * 3 + 1], w2q = wqr[dy * 3 + 2];
            float w0k = wkr[dy * 3], w1k = wkr[dy * 3 + 1], w2k = wkr[dy * 3 + 2];
            #pragma unroll
            for (int j = 0; j < 8; ++j) {
                acq[j] += w0q * r[j] + w1q * r[j + 1] + w2q * r[j + 2];
                ack[j] += w0k * r[j] + w1k * r[j + 1] + w2k * r[j + 2];
            }
        }
        int s = tt * 64 + py * 8 + px;
        size_t off = ((size_t)b * S_ + s) * D_ + (size_t)c * 64 + ky * 8;
        unsigned short pq[8], pk[8];
        #pragma unroll
        for (int j = 0; j < 8; ++j) { pq[j] = f2bf(acq[j]); pk[j] = f2bf(ack[j]); }
        *(short8v*)(Qp + off) = *(const short8v*)pq;
        *(short8v*)(Kp + off) = *(const short8v*)pk;
    }
}

// ---------------- 3/7) dense 3x3 conv: implicit-GEMM MFMA -------------------
// r6 compute/epilogue (known-good) + tap-level double-buffered wl:
// per tap: {issue next-tap W loads to regs; sched_barrier; compute 32 MFMA
// from wl[tap&1]; ds_write next tap to wl[(tap+1)&1]; barrier}. One barrier
// per tap, stage latency hidden under MFMA. LDS 50688+16384=67072 -> 2 blk/CU.
template<bool IS_V>
__global__ __launch_bounds__(256, 2) void conv_mfma4(
    const void* __restrict__ src,                 // IS_V: f32 x ; else bf16 FEAT
    const __hip_bfloat16* __restrict__ Wt,        // [9][64][64] bf16
    const float* __restrict__ bias,
    const float* __restrict__ xin,                // residual input (conv_c)
    void* __restrict__ dst)                       // IS_V: bf16 V ; else f32 out
{
    __shared__ char xs[6 * 66 * 128];             // 50688 B
    __shared__ char wl[2][64 * 128];              // 16384 B
    const int f    = blockIdx.y;
    const int band = blockIdx.x;                  // 0..15
    const int y0   = band * 4;
    const int tid  = threadIdx.x;
    const int lane = tid & 63;
    const int w    = tid >> 6;
    const int q    = lane >> 4;
    const int l15  = lane & 15;

    // per-thread weight-staging coords (512 chunks of 16B per tap, 2/thread)
    const unsigned short* Wg = (const unsigned short*)Wt;
    const int r0w = tid >> 3, c0w = (tid & 7) * 8;
    const int wlo = r0w * 128 + ((c0w * 2) ^ ((r0w & 7) << 4));
    const unsigned short* wgl = Wg + r0w * 64 + c0w;

    // issue tap-0 weight loads first (latency hidden under xs staging)
    short8v w0A = *(const short8v*)(wgl);
    short8v w0B = *(const short8v*)(wgl + 2048);

    // ---- stage xs: input rows y0-1 .. y0+4
    for (int e = tid; e < 6 * 16 * 64; e += 256) {
        int x  = e & 63;
        int cg = (e >> 6) & 15;
        int r  = e >> 10;
        int y  = y0 - 1 + r;
        unsigned short p[4];
        if ((unsigned)y < (unsigned)H_) {
            #pragma unroll
            for (int j = 0; j < 4; ++j) {
                size_t gi = (((size_t)f * C_ + cg * 4 + j) * H_ + y) * W_ + x;
                if constexpr (IS_V) p[j] = f2bf(((const float*)src)[gi]);
                else                p[j] = ((const unsigned short*)src)[gi];
            }
        } else { p[0] = p[1] = p[2] = p[3] = 0; }
        int xp = x + 1;
        int byte = (r * 66 + xp) * 128 + ((cg * 8) ^ ((xp & 7) << 4));
        *(uint2*)(xs + byte) = *(uint2*)p;
    }
    for (int e = tid; e < 6 * 16 * 2; e += 256) {
        int side = e & 1;
        int cg   = (e >> 1) & 15;
        int r    = e >> 5;
        int xp   = side ? 65 : 0;
        int byte = (r * 66 + xp) * 128 + ((cg * 8) ^ ((xp & 7) << 4));
        *(uint2*)(xs + byte) = uint2{0u, 0u};
    }
    // write tap-0 weights
    *(short8v*)(wl[0] + wlo) = w0A;
    *(short8v*)(wl[0] + wlo + 32 * 128) = w0B;
    __syncthreads();

    float4v acc[4][4] = {};
    #pragma unroll
    for (int tap = 0; tap < 9; ++tap) {
        const int ky = tap / 3, kx = tap - ky * 3;
        short8v nwA, nwB;
        if (tap + 1 < 9) {                        // constant-folds per unroll
            nwA = *(const short8v*)(wgl + (tap + 1) * 4096);
            nwB = *(const short8v*)(wgl + (tap + 1) * 4096 + 2048);
            __builtin_amdgcn_sched_barrier(0);    // pin: don't sink loads
        }
        const char* wb = wl[tap & 1];
        const int ri = w + ky;                    // xs row slot for this wave
        #pragma unroll
        for (int kc = 0; kc < 2; ++kc) {
            int kB = kc * 64 + q * 16;
            short8v bfr[4];
            #pragma unroll
            for (int nt = 0; nt < 4; ++nt)
                bfr[nt] = frag_ld(wb, nt * 16 + l15, kB);
            #pragma unroll
            for (int xt = 0; xt < 4; ++xt) {
                int xp = xt * 16 + l15 + kx;
                short8v av = *(const short8v*)(xs + (ri * 66 + xp) * 128 +
                                               (kB ^ ((xp & 7) << 4)));
                #pragma unroll
                for (int nt = 0; nt < 4; ++nt)
                    acc[xt][nt] = __builtin_amdgcn_mfma_f32_16x16x32_bf16(
                        av, bfr[nt], acc[xt][nt], 0, 0, 0);
            }
        }
        if (tap + 1 < 9) {
            char* wn = wl[(tap + 1) & 1];
            *(short8v*)(wn + wlo) = nwA;
            *(short8v*)(wn + wlo + 32 * 128) = nwB;
        }
        __syncthreads();
    }

    // ---- epilogue: D col(l15)=co, row(q*4+j)=x
    float bco[4];
    #pragma unroll
    for (int nt = 0; nt < 4; ++nt) bco[nt] = bias[nt * 16 + l15];
    const int bb = f / T_, tt = f % T_;
    const int R = y0 + w;
    #pragma unroll
    for (int xt = 0; xt < 4; ++xt) {
        #pragma unroll
        for (int nt = 0; nt < 4; ++nt) {
            int co = nt * 16 + l15;
            if constexpr (IS_V) {
                int s  = tt * 64 + (R >> 3) * 8 + xt * 2 + (q >> 1);
                int d0 = co * 64 + (R & 7) * 8 + (q & 1) * 4;
                unsigned short pk[4];
                #pragma unroll
                for (int j = 0; j < 4; ++j)
                    pk[j] = f2bf(acc[xt][nt][j] + bco[nt]);
                *(uint2*)((unsigned short*)dst + ((size_t)bb * S_ + s) * D_ + d0) =
                    *(const uint2*)pk;
            } else {
                size_t o = (((size_t)f * C_ + co) * H_ + R) * W_ + xt * 16 + q * 4;
                float4 rv = *(const float4*)(xin + o);
                float4 ov;
                ov.x = acc[xt][nt][0] + bco[nt] + rv.x;
                ov.y = acc[xt][nt][1] + bco[nt] + rv.y;
                ov.z = acc[xt][nt][2] + bco[nt] + rv.z;
                ov.w = acc[xt][nt][3] + bco[nt] + rv.w;
                *(float4*)((float*)dst + o) = ov;
            }
        }
    }
}

// ---------------- 4) ATTN = (1/64) Q K^T via MFMA ---------------------------
__global__ __launch_bounds__(512, 2) void gemm_qk_mfma(
    const __hip_bfloat16* __restrict__ Qg,
    const __hip_bfloat16* __restrict__ Kg,
    float* __restrict__ ATTN)
{
    __shared__ alignas(16) char lds[32768];
    char* ldsA = lds;
    char* ldsB = lds + 16384;
    int bid = blockIdx.x;
    int lb  = (bid & 7) * 32 + (bid >> 3);
    int bb  = lb >> 4;
    int m0  = ((lb >> 2) & 3) * 128;
    int n0  = (lb & 3) * 128;
    const unsigned short* Ag = (const unsigned short*)Qg + (size_t)bb * S_ * D_ + (size_t)m0 * D_;
    const unsigned short* Bg = (const unsigned short*)Kg + (size_t)bb * S_ * D_ + (size_t)n0 * D_;
    int t = threadIdx.x;
    int w = t >> 6, l = t & 63, q = l >> 4, l15 = l & 15;
    int wm = w >> 2, wn = w & 3;
    int r0 = t >> 3, c0 = (t & 7) * 8;
    int r1 = 64 + r0;
    short8v sA0, sA1, sB0, sB1;
    sA0 = *(const short8v*)(Ag + (size_t)r0 * D_ + c0);
    sA1 = *(const short8v*)(Ag + (size_t)r1 * D_ + c0);
    sB0 = *(const short8v*)(Bg + (size_t)r0 * D_ + c0);
    sB1 = *(const short8v*)(Bg + (size_t)r1 * D_ + c0);

    float4v acc[4][2] = {};
    int swz0 = (c0 * 2) ^ ((r0 & 7) << 4);
    for (int k0 = 0; k0 < D_; k0 += 64) {
        __syncthreads();
        *(short8v*)(ldsA + r0 * 128 + swz0) = sA0;
        *(short8v*)(ldsA + r1 * 128 + swz0) = sA1;
        *(short8v*)(ldsB + r0 * 128 + swz0) = sB0;
        *(short8v*)(ldsB + r1 * 128 + swz0) = sB1;
        if (k0 + 64 < D_) {
            int kn = k0 + 64;
            sA0 = *(const short8v*)(Ag + (size_t)r0 * D_ + kn + c0);
            sA1 = *(const short8v*)(Ag + (size_t)r1 * D_ + kn + c0);
            sB0 = *(const short8v*)(Bg + (size_t)r0 * D_ + kn + c0);
            sB1 = *(const short8v*)(Bg + (size_t)r1 * D_ + kn + c0);
        }
        __syncthreads();
        #pragma unroll
        for (int kc = 0; kc < 2; ++kc) {
            int kB = kc * 64 + q * 16;
            short8v a[4], b[2];
            #pragma unroll
            for (int mt = 0; mt < 4; ++mt) a[mt] = frag_ld(ldsA, wm * 64 + mt * 16 + l15, kB);
            #pragma unroll
            for (int nt = 0; nt < 2; ++nt) b[nt] = frag_ld(ldsB, wn * 32 + nt * 16 + l15, kB);
            #pragma unroll
            for (int mt = 0; mt < 4; ++mt)
                #pragma unroll
                for (int nt = 0; nt < 2; ++nt)
                    acc[mt][nt] = __builtin_amdgcn_mfma_f32_16x16x32_bf16(
                        a[mt], b[nt], acc[mt][nt], 0, 0, 0);
        }
    }
    const float scale = 1.0f / 64.0f;
    #pragma unroll
    for (int mt = 0; mt < 4; ++mt) {
        #pragma unroll
        for (int nt = 0; nt < 2; ++nt) {
            int u = n0 + wn * 32 + nt * 16 + l15;
            #pragma unroll
            for (int j = 0; j < 4; ++j) {
                int s = m0 + wm * 64 + mt * 16 + q * 4 + j;
                if (s < S_ && u < S_)
                    ATTN[((size_t)bb * S_ + s) * S_ + u] = acc[mt][nt][j] * scale;
            }
        }
    }
}

// ---------------- 5) row softmax -> bf16 P ----------------------------------
__global__ __launch_bounds__(64) void softmax_rows(const float* __restrict__ ATTN,
                                                   unsigned short* __restrict__ P)
{
    size_t row = blockIdx.x;
    const float* p = ATTN + row * S_;
    int lane = threadIdx.x;
    float vals[7];
    float m = -1e30f;
    #pragma unroll
    for (int i = 0; i < 7; ++i) { vals[i] = p[lane + i * 64]; m = fmaxf(m, vals[i]); }
    #pragma unroll
    for (int off = 32; off; off >>= 1) m = fmaxf(m, __shfl_xor(m, off));
    float sum = 0.f;
    #pragma unroll
    for (int i = 0; i < 7; ++i) { vals[i] = __expf(vals[i] - m); sum += vals[i]; }
    #pragma unroll
    for (int off = 32; off; off >>= 1) sum += __shfl_xor(sum, off);
    float inv = 1.f / sum;
    #pragma unroll
    for (int i = 0; i < 7; ++i) P[row * S_ + lane + i * 64] = f2bf(vals[i] * inv);
}

// ---------------- 6) FEAT = P @ V via MFMA (V transposed in LDS) ------------
__global__ __launch_bounds__(256, 2) void gemm_pv_mfma(
    const unsigned short* __restrict__ Pg,
    const __hip_bfloat16* __restrict__ Vg,
    __hip_bfloat16* __restrict__ FEAT)
{
    __shared__ alignas(16) char lds[32768];
    char* ldsA = lds;
    char* ldsB = lds + 16384;
    int bid = blockIdx.x;
    int lb  = (bid & 7) * 256 + (bid >> 3);
    int bb  = lb >> 7;
    int tl  = lb & 127;
    int m0  = (tl >> 5) * 128;
    int n0  = (tl & 31) * 128;
    const unsigned short* Ag = Pg + (size_t)bb * S_ * S_ + (size_t)m0 * S_;
    const unsigned short* Bg = (const unsigned short*)Vg + (size_t)bb * S_ * D_ + n0;
    int t = threadIdx.x;
    int w = t >> 6, l = t & 63, q = l >> 4, l15 = l & 15;
    int wm = w >> 1, wn = w & 1;
    float4v acc[4][4] = {};
    for (int k0 = 0; k0 < S_; k0 += 64) {
        __syncthreads();
        stage_tile<256>(ldsA, Ag + k0, S_, t);
        stage_vt(ldsB, Bg + (size_t)k0 * D_, t);
        __syncthreads();
        #pragma unroll
        for (int kc = 0; kc < 2; ++kc) {
            int kB = kc * 64 + q * 16;
            short8v a[4], b[4];
            #pragma unroll
            for (int mt = 0; mt < 4; ++mt) a[mt] = frag_ld(ldsA, wm * 64 + mt * 16 + l15, kB);
            #pragma unroll
            for (int nt = 0; nt < 4; ++nt) b[nt] = frag_ld(ldsB, wn * 64 + nt * 16 + l15, kB);
            #pragma unroll
            for (int mt = 0; mt < 4; ++mt)
                #pragma unroll
                for (int nt = 0; nt < 4; ++nt)
                    acc[mt][nt] = __builtin_amdgcn_mfma_f32_16x16x32_bf16(
                        a[mt], b[nt], acc[mt][nt], 0, 0, 0);
        }
    }
    #pragma unroll
    for (int mt = 0; mt < 4; ++mt) {
        #pragma unroll
        for (int j = 0; j < 4; ++j) {
            int s = m0 + wm * 64 + mt * 16 + q * 4 + j;
            if (s >= S_) continue;
            int f  = bb * T_ + (s >> 6);
            int l6 = s & 63;
            #pragma unroll
            for (int nt = 0; nt < 4; ++nt) {
                int d = n0 + wn * 64 + nt * 16 + l15;
                int c = d >> 6, r = d & 63;
                int y  = ((l6 >> 3) << 3) + (r >> 3);
                int xx = ((l6 & 7) << 3) + (r & 7);
                FEAT[(((size_t)f * C_ + c) * H_ + y) * W_ + xx] =
                    __float2bfloat16(acc[mt][nt][j]);
            }
        }
    }
}

// ---------------------------------------------------------------------------
extern "C" void kernel_launch(void* const* d_in, const int* in_sizes, int n_in,
                              void* d_out, int out_size, void* d_ws, size_t ws_size,
                              hipStream_t stream)
{
    const float* x  = (const float*)d_in[0];
    const float* wq = (const float*)d_in[1];
    const float* bq = (const float*)d_in[2];
    const float* wk = (const float*)d_in[3];
    const float* bk = (const float*)d_in[4];
    const float* wv = (const float*)d_in[5];
    const float* bv = (const float*)d_in[6];
    const float* wc = (const float*)d_in[7];
    const float* bc = (const float*)d_in[8];
    float* out = (float*)d_out;

    __hip_bfloat16* Qb = (__hip_bfloat16*)d_ws;
    __hip_bfloat16* Kb = Qb + QKV_E;
    __hip_bfloat16* Vb = Kb + QKV_E;
    float* ATTN = (float*)(Vb + QKV_E);
    __hip_bfloat16* Wt_v = (__hip_bfloat16*)(ATTN + ATTN_E);
    __hip_bfloat16* Wt_c = Wt_v + 9 * 64 * 64;
    unsigned short* Pb   = (unsigned short*)Kb;   // aliases Kb (dead after qk)
    __hip_bfloat16* FEAT = Qb;                    // aliases Qb (dead after qk)

    prep_w2<<<288, 256, 0, stream>>>(wv, wc, Wt_v, Wt_c);

    conv_qk_unfold3<<<dim3(8, 8, NFR), 256, 0, stream>>>(x, wq, bq, wk, bk, Qb, Kb);
    conv_mfma4<true><<<dim3(16, NFR), 256, 0, stream>>>(x, Wt_v, bv, nullptr, Vb);
    gemm_qk_mfma<<<256, 512, 0, stream>>>(Qb, Kb, ATTN);
    softmax_rows<<<B_ * S_, 64, 0, stream>>>(ATTN, Pb);
    gemm_pv_mfma<<<2048, 256, 0, stream>>>(Pb, Vb, FEAT);
    conv_mfma4<false><<<dim3(16, NFR), 256, 0, stream>>>(FEAT, Wt_c, bc, x, out);
}

// Round 10
// 368.679 us; speedup vs baseline: 1.2937x; 1.0782x over previous
//
#include <hip/hip_runtime.h>
#include <hip/hip_bf16.h>

// ---------------------------------------------------------------------------
// globalAttention: b=16 t=7 c=64 h=w=64, P=8  ->  112 frames, S=448, D=4096
//   1) prep_w2        : wv,wc fp32 [co][ci][3][3] -> bf16 Wt[r][co][ci] (fused)
//   2) conv_qk_unfold3: depthwise 3x3 conv (q,k); x staged via LDS
//   3) conv_mfma5<V>  : dense conv v, MFMA implicit GEMM; 512thr/8 waves
//                       (wave = row x co-half), wl tap-dbuf, 16 waves/CU (r10)
//   4) gemm_qk_mfma   : ATTN = (1/64) Q K^T   (bf16 MFMA, fp32 out)
//   5) softmax_rows   : row softmax -> bf16 P  (P aliases Kb)
//   6) gemm_pv_mfma   : FEAT[f][c][y][x] bf16 = P @ V   (V transposed in LDS)
//   7) conv_mfma5<C>  : dense conv c + bias + residual -> d_out
// Workspace: Qb[58.7M] Kb[58.7M] Vb[58.7M] ATTN[12.8M] Wt[144K]
// P(bf16) aliases Kb; FEAT(bf16) aliases Qb. Total ~189.5 MiB.
// ---------------------------------------------------------------------------

namespace {
constexpr int NFR = 112;
constexpr int T_  = 7;
constexpr int B_  = 16;
constexpr int C_  = 64;
constexpr int H_  = 64;
constexpr int W_  = 64;
constexpr int S_  = 448;
constexpr int D_  = 4096;
constexpr size_t QKV_E = (size_t)B_ * S_ * D_;
constexpr size_t ATTN_E = (size_t)B_ * S_ * S_;
}

typedef __attribute__((ext_vector_type(8))) short short8v;
typedef __attribute__((ext_vector_type(4))) float float4v;

__device__ __forceinline__ float bfu2f(unsigned short u) {
    union { unsigned int i; float f; } v; v.i = ((unsigned int)u) << 16; return v.f;
}
__device__ __forceinline__ unsigned short f2bf(float f) {
    __hip_bfloat16 h = __float2bfloat16(f);
    return *reinterpret_cast<unsigned short*>(&h);
}

// element (r, k) of a Rx64-short tile lives at byte r*128 + ((2k)^((r&7)<<4))
__device__ __forceinline__ short8v frag_ld(const char* ldsb, int r, int kByte) {
    return *(const short8v*)(ldsb + r * 128 + (kByte ^ ((r & 7) << 4)));
}

// stage 128 rows x 64 shorts from g (row stride ldg shorts) into swizzled LDS
template<int NTHR>
__device__ __forceinline__ void stage_tile(char* ldsb, const unsigned short* g,
                                           int ldg, int t) {
    #pragma unroll
    for (int i = 0; i < 1024 / NTHR; ++i) {
        int e = i * NTHR + t;
        int r = e >> 3, c8 = (e & 7) * 8;
        short8v v = *(const short8v*)(g + (size_t)r * ldg + c8);
        *(short8v*)(ldsb + r * 128 + ((c8 * 2) ^ ((r & 7) << 4))) = v;
    }
}

// stage V[u][d] tile (64 u x 128 d) TRANSPOSED into LDS as [d][u] swizzled
__device__ __forceinline__ void stage_vt(char* ldsb, const unsigned short* g, int t) {
    int d0 = (t & 15) * 8;
    int u0 = (t >> 4) * 4;
    short8v r0 = *(const short8v*)(g + (size_t)(u0 + 0) * D_ + d0);
    short8v r1 = *(const short8v*)(g + (size_t)(u0 + 1) * D_ + d0);
    short8v r2 = *(const short8v*)(g + (size_t)(u0 + 2) * D_ + d0);
    short8v r3 = *(const short8v*)(g + (size_t)(u0 + 3) * D_ + d0);
    #pragma unroll
    for (int j = 0; j < 8; ++j) {
        unsigned int lo = (unsigned short)r0[j] | (((unsigned int)(unsigned short)r1[j]) << 16);
        unsigned int hi = (unsigned short)r2[j] | (((unsigned int)(unsigned short)r3[j]) << 16);
        int d = d0 + j;
        int byte = d * 128 + (((unsigned)(u0 * 2)) ^ ((d & 7) << 4));
        *(uint2*)(ldsb + byte) = uint2{lo, hi};
    }
}

// ---------------- 1) fused weight transpose (wv+wc) -------------------------
__global__ __launch_bounds__(256) void prep_w2(const float* __restrict__ wv,
                                               const float* __restrict__ wc,
                                               __hip_bfloat16* __restrict__ Wt_v,
                                               __hip_bfloat16* __restrict__ Wt_c)
{
    int t = blockIdx.x * 256 + threadIdx.x;          // 2*36864 = 73728
    if (t >= 2 * 36864) return;
    int which = t >= 36864;
    int i = t - which * 36864;
    const float* s = which ? wc : wv;
    __hip_bfloat16* d = which ? Wt_c : Wt_v;
    int r = i >> 12, co = (i >> 6) & 63, ci = i & 63;
    d[i] = __float2bfloat16(s[(co * 64 + ci) * 9 + r]);
}

// ---------------- 2) depthwise conv q,k + unfold, LDS-staged x --------------
__global__ __launch_bounds__(256) void conv_qk_unfold3(
    const float* __restrict__ x,
    const float* __restrict__ wq, const float* __restrict__ bq,
    const float* __restrict__ wk, const float* __restrict__ bk,
    __hip_bfloat16* __restrict__ Q, __hip_bfloat16* __restrict__ K)
{
    __shared__ float xls[8][10][67];
    int py  = blockIdx.x;          // 0..7
    int oc8 = blockIdx.y;          // 0..7
    int f   = blockIdx.z;          // 0..111
    int t = threadIdx.x;
    int yb = py * 8 - 1;

    for (int e = t; e < 8 * 10 * 64; e += 256) {
        int col = e & 63;
        int row = (e >> 6) % 10;
        int ch  = e / 640;
        int y = yb + row;
        float v = 0.f;
        if ((unsigned)y < (unsigned)H_)
            v = x[(((size_t)f * C_ + oc8 * 8 + ch) * H_ + y) * W_ + col];
        xls[ch][row][col + 1] = v;
    }
    for (int e = t; e < 8 * 10 * 3; e += 256) {
        int which = e % 3;
        int row = (e / 3) % 10;
        int ch  = e / 30;
        xls[ch][row][which == 0 ? 0 : 64 + which] = 0.f;
    }
    __syncthreads();

    int w = t >> 6, lane = t & 63;
    int cg = lane >> 3, ky = lane & 7;
    int c  = oc8 * 8 + cg;
    float wqr[9], wkr[9];
    #pragma unroll
    for (int i = 0; i < 9; ++i) { wqr[i] = wq[c * 9 + i]; wkr[i] = wk[c * 9 + i]; }
    float bqv = bq[c], bkv = bk[c];
    int b = f / T_, tt = f % T_;
    unsigned short* Qp = (unsigned short*)Q;
    unsigned short* Kp = (unsigned short*)K;

    #pragma unroll
    for (int pi = 0; pi < 2; ++pi) {
        int px = w + pi * 4;
        int xb = px * 8;
        float acq[8], ack[8];
        #pragma unroll
        for (int j = 0; j < 8; ++j) { acq[j] = bqv; ack[j] = bkv; }
        #pragma unroll
        for (int dy = 0; dy < 3; ++dy) {
            const float* rp = &xls[cg][ky + dy][xb];   // cols xb-1 .. xb+8
            float r[10];
            #pragma unroll
            for (int j = 0; j < 10; ++j) r[j] = rp[j];
            float w0q = wqr[dy * 3], w1q = wqr[dy * 3 + 1], w2q = wqr[dy * 3 + 2];
            float w0k = wkr[dy * 3], w1k = wkr[dy * 3 + 1], w2k = wkr[dy * 3 + 2];
            #pragma unroll
            for (int j = 0; j < 8; ++j) {
                acq[j] += w0q * r[j] + w1q * r[j + 1] + w2q * r[j + 2];
                ack[j] += w0k * r[j] + w1k * r[j + 1] + w2k * r[j + 2];
            }
        }
        int s = tt * 64 + py * 8 + px;
        size_t off = ((size_t)b * S_ + s) * D_ + (size_t)c * 64 + ky * 8;
        unsigned short pq[8], pk[8];
        #pragma unroll
        for (int j = 0; j < 8; ++j) { pq[j] = f2bf(acq[j]); pk[j] = f2bf(ack[j]); }
        *(short8v*)(Qp + off) = *(const short8v*)pq;
        *(short8v*)(Kp + off) = *(const short8v*)pk;
    }
}

// ---------------- 3/7) dense 3x3 conv: implicit-GEMM MFMA, 8 waves ----------
// Block: frame x 4-row band, 512 threads / 8 waves. Wave w: output row
// y0+(w>>1), co-half (w&1) -> per-wave tile M=64(x) x N=32(co). wl tap-level
// double-buffer (1 barrier/tap). LDS 50688+16384=67072 -> 2 blk/CU =
// 16 waves/CU (the r10 occupancy lever).
template<bool IS_V>
__global__ __launch_bounds__(512, 4) void conv_mfma5(
    const void* __restrict__ src,                 // IS_V: f32 x ; else bf16 FEAT
    const __hip_bfloat16* __restrict__ Wt,        // [9][64][64] bf16
    const float* __restrict__ bias,
    const float* __restrict__ xin,                // residual input (conv_c)
    void* __restrict__ dst)                       // IS_V: bf16 V ; else f32 out
{
    __shared__ char xs[6 * 66 * 128];             // 50688 B
    __shared__ char wl[2][64 * 128];              // 16384 B
    const int f    = blockIdx.y;
    const int band = blockIdx.x;                  // 0..15
    const int y0   = band * 4;
    const int tid  = threadIdx.x;
    const int lane = tid & 63;
    const int w    = tid >> 6;                    // 0..7
    const int q    = lane >> 4;
    const int l15  = lane & 15;
    const int wrow = w >> 1;                      // output row 0..3
    const int wco  = w & 1;                       // co half

    // per-thread weight-staging coords (512 chunks of 16B per tap, 1/thread)
    const unsigned short* Wg = (const unsigned short*)Wt;
    const int r0w = tid >> 3, c0w = (tid & 7) * 8;         // r0w 0..63
    const int wlo = r0w * 128 + ((c0w * 2) ^ ((r0w & 7) << 4));
    const unsigned short* wgl = Wg + r0w * 64 + c0w;

    // issue tap-0 weight load first (latency hidden under xs staging)
    short8v w0A = *(const short8v*)(wgl);

    // ---- stage xs: input rows y0-1 .. y0+4 (6144 chunks of 8B, 12/thread)
    for (int e = tid; e < 6 * 16 * 64; e += 512) {
        int x  = e & 63;
        int cg = (e >> 6) & 15;
        int r  = e >> 10;
        int y  = y0 - 1 + r;
        unsigned short p[4];
        if ((unsigned)y < (unsigned)H_) {
            #pragma unroll
            for (int j = 0; j < 4; ++j) {
                size_t gi = (((size_t)f * C_ + cg * 4 + j) * H_ + y) * W_ + x;
                if constexpr (IS_V) p[j] = f2bf(((const float*)src)[gi]);
                else                p[j] = ((const unsigned short*)src)[gi];
            }
        } else { p[0] = p[1] = p[2] = p[3] = 0; }
        int xp = x + 1;
        int byte = (r * 66 + xp) * 128 + ((cg * 8) ^ ((xp & 7) << 4));
        *(uint2*)(xs + byte) = *(uint2*)p;
    }
    for (int e = tid; e < 6 * 16 * 2; e += 512) {
        int side = e & 1;
        int cg   = (e >> 1) & 15;
        int r    = e >> 5;
        int xp   = side ? 65 : 0;
        int byte = (r * 66 + xp) * 128 + ((cg * 8) ^ ((xp & 7) << 4));
        *(uint2*)(xs + byte) = uint2{0u, 0u};
    }
    // write tap-0 weights
    *(short8v*)(wl[0] + wlo) = w0A;
    __syncthreads();

    float4v acc[4][2] = {};
    #pragma unroll
    for (int tap = 0; tap < 9; ++tap) {
        const int ky = tap / 3, kx = tap - ky * 3;
        short8v nwA;
        if (tap + 1 < 9) {                        // constant-folds per unroll
            nwA = *(const short8v*)(wgl + (tap + 1) * 4096);
            __builtin_amdgcn_sched_barrier(0);    // pin: don't sink loads
        }
        const char* wb = wl[tap & 1];
        const int ri = wrow + ky;                 // xs row slot for this wave
        #pragma unroll
        for (int kc = 0; kc < 2; ++kc) {
            int kB = kc * 64 + q * 16;
            short8v bfr[2];
            #pragma unroll
            for (int nt = 0; nt < 2; ++nt)
                bfr[nt] = frag_ld(wb, wco * 32 + nt * 16 + l15, kB);
            #pragma unroll
            for (int xt = 0; xt < 4; ++xt) {
                int xp = xt * 16 + l15 + kx;
                short8v av = *(const short8v*)(xs + (ri * 66 + xp) * 128 +
                                               (kB ^ ((xp & 7) << 4)));
                #pragma unroll
                for (int nt = 0; nt < 2; ++nt)
                    acc[xt][nt] = __builtin_amdgcn_mfma_f32_16x16x32_bf16(
                        av, bfr[nt], acc[xt][nt], 0, 0, 0);
            }
        }
        if (tap + 1 < 9) {
            *(short8v*)(wl[(tap + 1) & 1] + wlo) = nwA;
        }
        __syncthreads();
    }

    // ---- epilogue: D col(l15)=co-within-16, row(q*4+j)=x
    float bco[2];
    #pragma unroll
    for (int nt = 0; nt < 2; ++nt) bco[nt] = bias[wco * 32 + nt * 16 + l15];
    const int bb = f / T_, tt = f % T_;
    const int R = y0 + wrow;
    #pragma unroll
    for (int xt = 0; xt < 4; ++xt) {
        #pragma unroll
        for (int nt = 0; nt < 2; ++nt) {
            int co = wco * 32 + nt * 16 + l15;
            if constexpr (IS_V) {
                int s  = tt * 64 + (R >> 3) * 8 + xt * 2 + (q >> 1);
                int d0 = co * 64 + (R & 7) * 8 + (q & 1) * 4;
                unsigned short pk[4];
                #pragma unroll
                for (int j = 0; j < 4; ++j)
                    pk[j] = f2bf(acc[xt][nt][j] + bco[nt]);
                *(uint2*)((unsigned short*)dst + ((size_t)bb * S_ + s) * D_ + d0) =
                    *(const uint2*)pk;
            } else {
                size_t o = (((size_t)f * C_ + co) * H_ + R) * W_ + xt * 16 + q * 4;
                float4 rv = *(const float4*)(xin + o);
                float4 ov;
                ov.x = acc[xt][nt][0] + bco[nt] + rv.x;
                ov.y = acc[xt][nt][1] + bco[nt] + rv.y;
                ov.z = acc[xt][nt][2] + bco[nt] + rv.z;
                ov.w = acc[xt][nt][3] + bco[nt] + rv.w;
                *(float4*)((float*)dst + o) = ov;
            }
        }
    }
}

// ---------------- 4) ATTN = (1/64) Q K^T via MFMA ---------------------------
__global__ __launch_bounds__(512, 2) void gemm_qk_mfma(
    const __hip_bfloat16* __restrict__ Qg,
    const __hip_bfloat16* __restrict__ Kg,
    float* __restrict__ ATTN)
{
    __shared__ alignas(16) char lds[32768];
    char* ldsA = lds;
    char* ldsB = lds + 16384;
    int bid = blockIdx.x;
    int lb  = (bid & 7) * 32 + (bid >> 3);
    int bb  = lb >> 4;
    int m0  = ((lb >> 2) & 3) * 128;
    int n0  = (lb & 3) * 128;
    const unsigned short* Ag = (const unsigned short*)Qg + (size_t)bb * S_ * D_ + (size_t)m0 * D_;
    const unsigned short* Bg = (const unsigned short*)Kg + (size_t)bb * S_ * D_ + (size_t)n0 * D_;
    int t = threadIdx.x;
    int w = t >> 6, l = t & 63, q = l >> 4, l15 = l & 15;
    int wm = w >> 2, wn = w & 3;
    int r0 = t >> 3, c0 = (t & 7) * 8;
    int r1 = 64 + r0;
    short8v sA0, sA1, sB0, sB1;
    sA0 = *(const short8v*)(Ag + (size_t)r0 * D_ + c0);
    sA1 = *(const short8v*)(Ag + (size_t)r1 * D_ + c0);
    sB0 = *(const short8v*)(Bg + (size_t)r0 * D_ + c0);
    sB1 = *(const short8v*)(Bg + (size_t)r1 * D_ + c0);

    float4v acc[4][2] = {};
    int swz0 = (c0 * 2) ^ ((r0 & 7) << 4);
    for (int k0 = 0; k0 < D_; k0 += 64) {
        __syncthreads();
        *(short8v*)(ldsA + r0 * 128 + swz0) = sA0;
        *(short8v*)(ldsA + r1 * 128 + swz0) = sA1;
        *(short8v*)(ldsB + r0 * 128 + swz0) = sB0;
        *(short8v*)(ldsB + r1 * 128 + swz0) = sB1;
        if (k0 + 64 < D_) {
            int kn = k0 + 64;
            sA0 = *(const short8v*)(Ag + (size_t)r0 * D_ + kn + c0);
            sA1 = *(const short8v*)(Ag + (size_t)r1 * D_ + kn + c0);
            sB0 = *(const short8v*)(Bg + (size_t)r0 * D_ + kn + c0);
            sB1 = *(const short8v*)(Bg + (size_t)r1 * D_ + kn + c0);
        }
        __syncthreads();
        #pragma unroll
        for (int kc = 0; kc < 2; ++kc) {
            int kB = kc * 64 + q * 16;
            short8v a[4], b[2];
            #pragma unroll
            for (int mt = 0; mt < 4; ++mt) a[mt] = frag_ld(ldsA, wm * 64 + mt * 16 + l15, kB);
            #pragma unroll
            for (int nt = 0; nt < 2; ++nt) b[nt] = frag_ld(ldsB, wn * 32 + nt * 16 + l15, kB);
            #pragma unroll
            for (int mt = 0; mt < 4; ++mt)
                #pragma unroll
                for (int nt = 0; nt < 2; ++nt)
                    acc[mt][nt] = __builtin_amdgcn_mfma_f32_16x16x32_bf16(
                        a[mt], b[nt], acc[mt][nt], 0, 0, 0);
        }
    }
    const float scale = 1.0f / 64.0f;
    #pragma unroll
    for (int mt = 0; mt < 4; ++mt) {
        #pragma unroll
        for (int nt = 0; nt < 2; ++nt) {
            int u = n0 + wn * 32 + nt * 16 + l15;
            #pragma unroll
            for (int j = 0; j < 4; ++j) {
                int s = m0 + wm * 64 + mt * 16 + q * 4 + j;
                if (s < S_ && u < S_)
                    ATTN[((size_t)bb * S_ + s) * S_ + u] = acc[mt][nt][j] * scale;
            }
        }
    }
}

// ---------------- 5) row softmax -> bf16 P ----------------------------------
__global__ __launch_bounds__(64) void softmax_rows(const float* __restrict__ ATTN,
                                                   unsigned short* __restrict__ P)
{
    size_t row = blockIdx.x;
    const float* p = ATTN + row * S_;
    int lane = threadIdx.x;
    float vals[7];
    float m = -1e30f;
    #pragma unroll
    for (int i = 0; i < 7; ++i) { vals[i] = p[lane + i * 64]; m = fmaxf(m, vals[i]); }
    #pragma unroll
    for (int off = 32; off; off >>= 1) m = fmaxf(m, __shfl_xor(m, off));
    float sum = 0.f;
    #pragma unroll
    for (int i = 0; i < 7; ++i) { vals[i] = __expf(vals[i] - m); sum += vals[i]; }
    #pragma unroll
    for (int off = 32; off; off >>= 1) sum += __shfl_xor(sum, off);
    float inv = 1.f / sum;
    #pragma unroll
    for (int i = 0; i < 7; ++i) P[row * S_ + lane + i * 64] = f2bf(vals[i] * inv);
}

// ---------------- 6) FEAT = P @ V via MFMA (V transposed in LDS) ------------
__global__ __launch_bounds__(256, 2) void gemm_pv_mfma(
    const unsigned short* __restrict__ Pg,
    const __hip_bfloat16* __restrict__ Vg,
    __hip_bfloat16* __restrict__ FEAT)
{
    __shared__ alignas(16) char lds[32768];
    char* ldsA = lds;
    char* ldsB = lds + 16384;
    int bid = blockIdx.x;
    int lb  = (bid & 7) * 256 + (bid >> 3);
    int bb  = lb >> 7;
    int tl  = lb & 127;
    int m0  = (tl >> 5) * 128;
    int n0  = (tl & 31) * 128;
    const unsigned short* Ag = Pg + (size_t)bb * S_ * S_ + (size_t)m0 * S_;
    const unsigned short* Bg = (const unsigned short*)Vg + (size_t)bb * S_ * D_ + n0;
    int t = threadIdx.x;
    int w = t >> 6, l = t & 63, q = l >> 4, l15 = l & 15;
    int wm = w >> 1, wn = w & 1;
    float4v acc[4][4] = {};
    for (int k0 = 0; k0 < S_; k0 += 64) {
        __syncthreads();
        stage_tile<256>(ldsA, Ag + k0, S_, t);
        stage_vt(ldsB, Bg + (size_t)k0 * D_, t);
        __syncthreads();
        #pragma unroll
        for (int kc = 0; kc < 2; ++kc) {
            int kB = kc * 64 + q * 16;
            short8v a[4], b[4];
            #pragma unroll
            for (int mt = 0; mt < 4; ++mt) a[mt] = frag_ld(ldsA, wm * 64 + mt * 16 + l15, kB);
            #pragma unroll
            for (int nt = 0; nt < 4; ++nt) b[nt] = frag_ld(ldsB, wn * 64 + nt * 16 + l15, kB);
            #pragma unroll
            for (int mt = 0; mt < 4; ++mt)
                #pragma unroll
                for (int nt = 0; nt < 4; ++nt)
                    acc[mt][nt] = __builtin_amdgcn_mfma_f32_16x16x32_bf16(
                        a[mt], b[nt], acc[mt][nt], 0, 0, 0);
        }
    }
    #pragma unroll
    for (int mt = 0; mt < 4; ++mt) {
        #pragma unroll
        for (int j = 0; j < 4; ++j) {
            int s = m0 + wm * 64 + mt * 16 + q * 4 + j;
            if (s >= S_) continue;
            int f  = bb * T_ + (s >> 6);
            int l6 = s & 63;
            #pragma unroll
            for (int nt = 0; nt < 4; ++nt) {
                int d = n0 + wn * 64 + nt * 16 + l15;
                int c = d >> 6, r = d & 63;
                int y  = ((l6 >> 3) << 3) + (r >> 3);
                int xx = ((l6 & 7) << 3) + (r & 7);
                FEAT[(((size_t)f * C_ + c) * H_ + y) * W_ + xx] =
                    __float2bfloat16(acc[mt][nt][j]);
            }
        }
    }
}

// ---------------------------------------------------------------------------
extern "C" void kernel_launch(void* const* d_in, const int* in_sizes, int n_in,
                              void* d_out, int out_size, void* d_ws, size_t ws_size,
                              hipStream_t stream)
{
    const float* x  = (const float*)d_in[0];
    const float* wq = (const float*)d_in[1];
    const float* bq = (const float*)d_in[2];
    const float* wk = (const float*)d_in[3];
    const float* bk = (const float*)d_in[4];
    const float* wv = (const float*)d_in[5];
    const float* bv = (const float*)d_in[6];
    const float* wc = (const float*)d_in[7];
    const float* bc = (const float*)d_in[8];
    float* out = (float*)d_out;

    __hip_bfloat16* Qb = (__hip_bfloat16*)d_ws;
    __hip_bfloat16* Kb = Qb + QKV_E;
    __hip_bfloat16* Vb = Kb + QKV_E;
    float* ATTN = (float*)(Vb + QKV_E);
    __hip_bfloat16* Wt_v = (__hip_bfloat16*)(ATTN + ATTN_E);
    __hip_bfloat16* Wt_c = Wt_v + 9 * 64 * 64;
    unsigned short* Pb   = (unsigned short*)Kb;   // aliases Kb (dead after qk)
    __hip_bfloat16* FEAT = Qb;                    // aliases Qb (dead after qk)

    prep_w2<<<288, 256, 0, stream>>>(wv, wc, Wt_v, Wt_c);

    conv_qk_unfold3<<<dim3(8, 8, NFR), 256, 0, stream>>>(x, wq, bq, wk, bk, Qb, Kb);
    conv_mfma5<true><<<dim3(16, NFR), 512, 0, stream>>>(x, Wt_v, bv, nullptr, Vb);
    gemm_qk_mfma<<<256, 512, 0, stream>>>(Qb, Kb, ATTN);
    softmax_rows<<<B_ * S_, 64, 0, stream>>>(ATTN, Pb);
    gemm_pv_mfma<<<2048, 256, 0, stream>>>(Pb, Vb, FEAT);
    conv_mfma5<false><<<dim3(16, NFR), 512, 0, stream>>>(FEAT, Wt_c, bc, x, out);
}

// Round 11
// 337.248 us; speedup vs baseline: 1.4143x; 1.0932x over previous
//
#include <hip/hip_runtime.h>
#include <hip/hip_bf16.h>

// ---------------------------------------------------------------------------
// globalAttention: b=16 t=7 c=64 h=w=64, P=8  ->  112 frames, S=448, D=4096
//   1) prep_w2        : wv,wc fp32 [co][ci][3][3] -> bf16 Wt[r][co][ci] (fused)
//   2) conv_mfma6<V>  : FUSED: dense conv v (MFMA, wl tap-dbuf, 8 waves)
//                       + depthwise conv q,k computed from the same xs slab
//                       (r11 lever: kills the separate conv_qk kernel)
//   3) gemm_qk_mfma   : ATTN = (1/64) Q K^T   (bf16 MFMA, fp32 out)
//   4) softmax_rows   : row softmax -> bf16 P  (P aliases Kb)
//   5) gemm_pv_mfma   : FEAT[f][c][y][x] bf16 = P @ V   (V transposed in LDS)
//   6) conv_mfma6<C>  : dense conv c + bias + residual -> d_out
// Workspace: Qb[58.7M] Kb[58.7M] Vb[58.7M] ATTN[12.8M] Wt[144K]
// P(bf16) aliases Kb; FEAT(bf16) aliases Qb. Total ~189.5 MiB.
// ---------------------------------------------------------------------------

namespace {
constexpr int NFR = 112;
constexpr int T_  = 7;
constexpr int B_  = 16;
constexpr int C_  = 64;
constexpr int H_  = 64;
constexpr int W_  = 64;
constexpr int S_  = 448;
constexpr int D_  = 4096;
constexpr size_t QKV_E = (size_t)B_ * S_ * D_;
constexpr size_t ATTN_E = (size_t)B_ * S_ * S_;
}

typedef __attribute__((ext_vector_type(8))) short short8v;
typedef __attribute__((ext_vector_type(4))) float float4v;

__device__ __forceinline__ float bfu2f(unsigned short u) {
    union { unsigned int i; float f; } v; v.i = ((unsigned int)u) << 16; return v.f;
}
__device__ __forceinline__ unsigned short f2bf(float f) {
    __hip_bfloat16 h = __float2bfloat16(f);
    return *reinterpret_cast<unsigned short*>(&h);
}

// element (r, k) of a Rx64-short tile lives at byte r*128 + ((2k)^((r&7)<<4))
__device__ __forceinline__ short8v frag_ld(const char* ldsb, int r, int kByte) {
    return *(const short8v*)(ldsb + r * 128 + (kByte ^ ((r & 7) << 4)));
}

// stage 128 rows x 64 shorts from g (row stride ldg shorts) into swizzled LDS
template<int NTHR>
__device__ __forceinline__ void stage_tile(char* ldsb, const unsigned short* g,
                                           int ldg, int t) {
    #pragma unroll
    for (int i = 0; i < 1024 / NTHR; ++i) {
        int e = i * NTHR + t;
        int r = e >> 3, c8 = (e & 7) * 8;
        short8v v = *(const short8v*)(g + (size_t)r * ldg + c8);
        *(short8v*)(ldsb + r * 128 + ((c8 * 2) ^ ((r & 7) << 4))) = v;
    }
}

// stage V[u][d] tile (64 u x 128 d) TRANSPOSED into LDS as [d][u] swizzled
__device__ __forceinline__ void stage_vt(char* ldsb, const unsigned short* g, int t) {
    int d0 = (t & 15) * 8;
    int u0 = (t >> 4) * 4;
    short8v r0 = *(const short8v*)(g + (size_t)(u0 + 0) * D_ + d0);
    short8v r1 = *(const short8v*)(g + (size_t)(u0 + 1) * D_ + d0);
    short8v r2 = *(const short8v*)(g + (size_t)(u0 + 2) * D_ + d0);
    short8v r3 = *(const short8v*)(g + (size_t)(u0 + 3) * D_ + d0);
    #pragma unroll
    for (int j = 0; j < 8; ++j) {
        unsigned int lo = (unsigned short)r0[j] | (((unsigned int)(unsigned short)r1[j]) << 16);
        unsigned int hi = (unsigned short)r2[j] | (((unsigned int)(unsigned short)r3[j]) << 16);
        int d = d0 + j;
        int byte = d * 128 + (((unsigned)(u0 * 2)) ^ ((d & 7) << 4));
        *(uint2*)(ldsb + byte) = uint2{lo, hi};
    }
}

// ---------------- 1) fused weight transpose (wv+wc) -------------------------
__global__ __launch_bounds__(256) void prep_w2(const float* __restrict__ wv,
                                               const float* __restrict__ wc,
                                               __hip_bfloat16* __restrict__ Wt_v,
                                               __hip_bfloat16* __restrict__ Wt_c)
{
    int t = blockIdx.x * 256 + threadIdx.x;          // 2*36864 = 73728
    if (t >= 2 * 36864) return;
    int which = t >= 36864;
    int i = t - which * 36864;
    const float* s = which ? wc : wv;
    __hip_bfloat16* d = which ? Wt_c : Wt_v;
    int r = i >> 12, co = (i >> 6) & 63, ci = i & 63;
    d[i] = __float2bfloat16(s[(co * 64 + ci) * 9 + r]);
}

// ---------------- 2/6) dense 3x3 conv MFMA (+ fused depthwise q,k) ----------
// Block: frame x 4-row band, 512 threads / 8 waves. Wave w: output row
// y0+(w>>1), co-half (w&1); wl tap-level double-buffer (1 barrier/tap).
// IS_V: also computes depthwise q,k conv from the same xs slab after the V
// epilogue (xs persists; weights wq/wk pre-staged to wqk_s).
// LDS: 50688 + 16384 (+5120 if IS_V) = 67072 / 72192 -> 2 blk/CU, 16 waves/CU.
template<bool IS_V>
__global__ __launch_bounds__(512, 4) void conv_mfma6(
    const void* __restrict__ src,                 // IS_V: f32 x ; else bf16 FEAT
    const __hip_bfloat16* __restrict__ Wt,        // [9][64][64] bf16
    const float* __restrict__ bias,
    const float* __restrict__ xin,                // residual input (conv_c)
    void* __restrict__ dst,                       // IS_V: bf16 V ; else f32 out
    const float* __restrict__ wq, const float* __restrict__ bq,
    const float* __restrict__ wk, const float* __restrict__ bk,
    unsigned short* __restrict__ Qout, unsigned short* __restrict__ Kout)
{
    __shared__ char xs[6 * 66 * 128];             // 50688 B
    __shared__ char wl[2][64 * 128];              // 16384 B
    __shared__ float wqk_s[IS_V ? 1280 : 1];      // wq[576] wk[576] bq[64] bk[64]
    const int f    = blockIdx.y;
    const int band = blockIdx.x;                  // 0..15
    const int y0   = band * 4;
    const int tid  = threadIdx.x;
    const int lane = tid & 63;
    const int w    = tid >> 6;                    // 0..7
    const int q    = lane >> 4;
    const int l15  = lane & 15;
    const int wrow = w >> 1;                      // output row 0..3
    const int wco  = w & 1;                       // co half

    // per-thread weight-staging coords (512 chunks of 16B per tap, 1/thread)
    const unsigned short* Wg = (const unsigned short*)Wt;
    const int r0w = tid >> 3, c0w = (tid & 7) * 8;         // r0w 0..63
    const int wlo = r0w * 128 + ((c0w * 2) ^ ((r0w & 7) << 4));
    const unsigned short* wgl = Wg + r0w * 64 + c0w;

    // issue tap-0 weight load first (latency hidden under xs staging)
    short8v w0A = *(const short8v*)(wgl);

    // ---- stage qk weights (IS_V only)
    if constexpr (IS_V) {
        for (int e = tid; e < 1280; e += 512) {
            float v;
            if (e < 576)       v = wq[e];
            else if (e < 1152) v = wk[e - 576];
            else if (e < 1216) v = bq[e - 1152];
            else               v = bk[e - 1216];
            wqk_s[e] = v;
        }
    }

    // ---- stage xs: input rows y0-1 .. y0+4 (6144 chunks of 8B, 12/thread)
    for (int e = tid; e < 6 * 16 * 64; e += 512) {
        int x  = e & 63;
        int cg = (e >> 6) & 15;
        int r  = e >> 10;
        int y  = y0 - 1 + r;
        unsigned short p[4];
        if ((unsigned)y < (unsigned)H_) {
            #pragma unroll
            for (int j = 0; j < 4; ++j) {
                size_t gi = (((size_t)f * C_ + cg * 4 + j) * H_ + y) * W_ + x;
                if constexpr (IS_V) p[j] = f2bf(((const float*)src)[gi]);
                else                p[j] = ((const unsigned short*)src)[gi];
            }
        } else { p[0] = p[1] = p[2] = p[3] = 0; }
        int xp = x + 1;
        int byte = (r * 66 + xp) * 128 + ((cg * 8) ^ ((xp & 7) << 4));
        *(uint2*)(xs + byte) = *(uint2*)p;
    }
    for (int e = tid; e < 6 * 16 * 2; e += 512) {
        int side = e & 1;
        int cg   = (e >> 1) & 15;
        int r    = e >> 5;
        int xp   = side ? 65 : 0;
        int byte = (r * 66 + xp) * 128 + ((cg * 8) ^ ((xp & 7) << 4));
        *(uint2*)(xs + byte) = uint2{0u, 0u};
    }
    // write tap-0 weights
    *(short8v*)(wl[0] + wlo) = w0A;
    __syncthreads();

    float4v acc[4][2] = {};
    #pragma unroll
    for (int tap = 0; tap < 9; ++tap) {
        const int ky = tap / 3, kx = tap - ky * 3;
        short8v nwA;
        if (tap + 1 < 9) {                        // constant-folds per unroll
            nwA = *(const short8v*)(wgl + (tap + 1) * 4096);
            __builtin_amdgcn_sched_barrier(0);    // pin: don't sink loads
        }
        const char* wb = wl[tap & 1];
        const int ri = wrow + ky;                 // xs row slot for this wave
        #pragma unroll
        for (int kc = 0; kc < 2; ++kc) {
            int kB = kc * 64 + q * 16;
            short8v bfr[2];
            #pragma unroll
            for (int nt = 0; nt < 2; ++nt)
                bfr[nt] = frag_ld(wb, wco * 32 + nt * 16 + l15, kB);
            #pragma unroll
            for (int xt = 0; xt < 4; ++xt) {
                int xp = xt * 16 + l15 + kx;
                short8v av = *(const short8v*)(xs + (ri * 66 + xp) * 128 +
                                               (kB ^ ((xp & 7) << 4)));
                #pragma unroll
                for (int nt = 0; nt < 2; ++nt)
                    acc[xt][nt] = __builtin_amdgcn_mfma_f32_16x16x32_bf16(
                        av, bfr[nt], acc[xt][nt], 0, 0, 0);
            }
        }
        if (tap + 1 < 9) {
            *(short8v*)(wl[(tap + 1) & 1] + wlo) = nwA;
        }
        __syncthreads();
    }

    // ---- epilogue: D col(l15)=co-within-16, row(q*4+j)=x
    float bco[2];
    #pragma unroll
    for (int nt = 0; nt < 2; ++nt) bco[nt] = bias[wco * 32 + nt * 16 + l15];
    const int bb = f / T_, tt = f % T_;
    const int R = y0 + wrow;
    #pragma unroll
    for (int xt = 0; xt < 4; ++xt) {
        #pragma unroll
        for (int nt = 0; nt < 2; ++nt) {
            int co = wco * 32 + nt * 16 + l15;
            if constexpr (IS_V) {
                int s  = tt * 64 + (R >> 3) * 8 + xt * 2 + (q >> 1);
                int d0 = co * 64 + (R & 7) * 8 + (q & 1) * 4;
                unsigned short pk[4];
                #pragma unroll
                for (int j = 0; j < 4; ++j)
                    pk[j] = f2bf(acc[xt][nt][j] + bco[nt]);
                *(uint2*)((unsigned short*)dst + ((size_t)bb * S_ + s) * D_ + d0) =
                    *(const uint2*)pk;
            } else {
                size_t o = (((size_t)f * C_ + co) * H_ + R) * W_ + xt * 16 + q * 4;
                float4 rv = *(const float4*)(xin + o);
                float4 ov;
                ov.x = acc[xt][nt][0] + bco[nt] + rv.x;
                ov.y = acc[xt][nt][1] + bco[nt] + rv.y;
                ov.z = acc[xt][nt][2] + bco[nt] + rv.z;
                ov.w = acc[xt][nt][3] + bco[nt] + rv.w;
                *(float4*)((float*)dst + o) = ov;
            }
        }
    }

    // ---- fused depthwise conv q,k from xs (IS_V only; acc registers dead) --
    if constexpr (IS_V) {
        const int cg8  = lane >> 3;          // 0..7 channel octant
        const int half = (lane >> 2) & 1;    // 0..1
        const int r2   = lane & 3;           // 0..3 row within band
        const int px   = w;                  // 0..7 patch col
        const int yk   = ((band & 1) << 2) + r2;        // y & 7
        const int s    = tt * 64 + (band >> 1) * 8 + px;
        #pragma unroll
        for (int p = 0; p < 2; ++p) {
            const int c0 = cg8 * 8 + half * 4 + p * 2;  // channels c0, c0+1
            float acq[2][8], ack[2][8];
            float bq0 = wqk_s[1152 + c0], bq1 = wqk_s[1152 + c0 + 1];
            float bk0 = wqk_s[1216 + c0], bk1 = wqk_s[1216 + c0 + 1];
            #pragma unroll
            for (int j = 0; j < 8; ++j) {
                acq[0][j] = bq0; acq[1][j] = bq1;
                ack[0][j] = bk0; ack[1][j] = bk1;
            }
            #pragma unroll
            for (int dy = 0; dy < 3; ++dy) {
                const int ri = r2 + dy;
                float rv0[10], rv1[10];
                #pragma unroll
                for (int u = 0; u < 10; ++u) {
                    int xp = px * 8 + u;
                    int byte = (ri * 66 + xp) * 128 + ((c0 * 2) ^ ((xp & 7) << 4));
                    unsigned int pr = *(const unsigned int*)(xs + byte);
                    rv0[u] = bfu2f((unsigned short)(pr & 0xffffu));
                    rv1[u] = bfu2f((unsigned short)(pr >> 16));
                }
                #pragma unroll
                for (int kx = 0; kx < 3; ++kx) {
                    float wq0 = wqk_s[c0 * 9 + dy * 3 + kx];
                    float wq1 = wqk_s[(c0 + 1) * 9 + dy * 3 + kx];
                    float wk0 = wqk_s[576 + c0 * 9 + dy * 3 + kx];
                    float wk1 = wqk_s[576 + (c0 + 1) * 9 + dy * 3 + kx];
                    #pragma unroll
                    for (int j = 0; j < 8; ++j) {
                        acq[0][j] += wq0 * rv0[j + kx];
                        acq[1][j] += wq1 * rv1[j + kx];
                        ack[0][j] += wk0 * rv0[j + kx];
                        ack[1][j] += wk1 * rv1[j + kx];
                    }
                }
            }
            #pragma unroll
            for (int i = 0; i < 2; ++i) {
                unsigned short pq[8], pk[8];
                #pragma unroll
                for (int j = 0; j < 8; ++j) {
                    pq[j] = f2bf(acq[i][j]);
                    pk[j] = f2bf(ack[i][j]);
                }
                size_t off = ((size_t)bb * S_ + s) * D_ + (size_t)(c0 + i) * 64 + yk * 8;
                *(short8v*)(Qout + off) = *(const short8v*)pq;
                *(short8v*)(Kout + off) = *(const short8v*)pk;
            }
        }
    }
}

// ---------------- 3) ATTN = (1/64) Q K^T via MFMA ---------------------------
__global__ __launch_bounds__(512, 2) void gemm_qk_mfma(
    const __hip_bfloat16* __restrict__ Qg,
    const __hip_bfloat16* __restrict__ Kg,
    float* __restrict__ ATTN)
{
    __shared__ alignas(16) char lds[32768];
    char* ldsA = lds;
    char* ldsB = lds + 16384;
    int bid = blockIdx.x;
    int lb  = (bid & 7) * 32 + (bid >> 3);
    int bb  = lb >> 4;
    int m0  = ((lb >> 2) & 3) * 128;
    int n0  = (lb & 3) * 128;
    const unsigned short* Ag = (const unsigned short*)Qg + (size_t)bb * S_ * D_ + (size_t)m0 * D_;
    const unsigned short* Bg = (const unsigned short*)Kg + (size_t)bb * S_ * D_ + (size_t)n0 * D_;
    int t = threadIdx.x;
    int w = t >> 6, l = t & 63, q = l >> 4, l15 = l & 15;
    int wm = w >> 2, wn = w & 3;
    int r0 = t >> 3, c0 = (t & 7) * 8;
    int r1 = 64 + r0;
    short8v sA0, sA1, sB0, sB1;
    sA0 = *(const short8v*)(Ag + (size_t)r0 * D_ + c0);
    sA1 = *(const short8v*)(Ag + (size_t)r1 * D_ + c0);
    sB0 = *(const short8v*)(Bg + (size_t)r0 * D_ + c0);
    sB1 = *(const short8v*)(Bg + (size_t)r1 * D_ + c0);

    float4v acc[4][2] = {};
    int swz0 = (c0 * 2) ^ ((r0 & 7) << 4);
    for (int k0 = 0; k0 < D_; k0 += 64) {
        __syncthreads();
        *(short8v*)(ldsA + r0 * 128 + swz0) = sA0;
        *(short8v*)(ldsA + r1 * 128 + swz0) = sA1;
        *(short8v*)(ldsB + r0 * 128 + swz0) = sB0;
        *(short8v*)(ldsB + r1 * 128 + swz0) = sB1;
        if (k0 + 64 < D_) {
            int kn = k0 + 64;
            sA0 = *(const short8v*)(Ag + (size_t)r0 * D_ + kn + c0);
            sA1 = *(const short8v*)(Ag + (size_t)r1 * D_ + kn + c0);
            sB0 = *(const short8v*)(Bg + (size_t)r0 * D_ + kn + c0);
            sB1 = *(const short8v*)(Bg + (size_t)r1 * D_ + kn + c0);
        }
        __syncthreads();
        #pragma unroll
        for (int kc = 0; kc < 2; ++kc) {
            int kB = kc * 64 + q * 16;
            short8v a[4], b[2];
            #pragma unroll
            for (int mt = 0; mt < 4; ++mt) a[mt] = frag_ld(ldsA, wm * 64 + mt * 16 + l15, kB);
            #pragma unroll
            for (int nt = 0; nt < 2; ++nt) b[nt] = frag_ld(ldsB, wn * 32 + nt * 16 + l15, kB);
            #pragma unroll
            for (int mt = 0; mt < 4; ++mt)
                #pragma unroll
                for (int nt = 0; nt < 2; ++nt)
                    acc[mt][nt] = __builtin_amdgcn_mfma_f32_16x16x32_bf16(
                        a[mt], b[nt], acc[mt][nt], 0, 0, 0);
        }
    }
    const float scale = 1.0f / 64.0f;
    #pragma unroll
    for (int mt = 0; mt < 4; ++mt) {
        #pragma unroll
        for (int nt = 0; nt < 2; ++nt) {
            int u = n0 + wn * 32 + nt * 16 + l15;
            #pragma unroll
            for (int j = 0; j < 4; ++j) {
                int s = m0 + wm * 64 + mt * 16 + q * 4 + j;
                if (s < S_ && u < S_)
                    ATTN[((size_t)bb * S_ + s) * S_ + u] = acc[mt][nt][j] * scale;
            }
        }
    }
}

// ---------------- 4) row softmax -> bf16 P ----------------------------------
__global__ __launch_bounds__(64) void softmax_rows(const float* __restrict__ ATTN,
                                                   unsigned short* __restrict__ P)
{
    size_t row = blockIdx.x;
    const float* p = ATTN + row * S_;
    int lane = threadIdx.x;
    float vals[7];
    float m = -1e30f;
    #pragma unroll
    for (int i = 0; i < 7; ++i) { vals[i] = p[lane + i * 64]; m = fmaxf(m, vals[i]); }
    #pragma unroll
    for (int off = 32; off; off >>= 1) m = fmaxf(m, __shfl_xor(m, off));
    float sum = 0.f;
    #pragma unroll
    for (int i = 0; i < 7; ++i) { vals[i] = __expf(vals[i] - m); sum += vals[i]; }
    #pragma unroll
    for (int off = 32; off; off >>= 1) sum += __shfl_xor(sum, off);
    float inv = 1.f / sum;
    #pragma unroll
    for (int i = 0; i < 7; ++i) P[row * S_ + lane + i * 64] = f2bf(vals[i] * inv);
}

// ---------------- 5) FEAT = P @ V via MFMA (V transposed in LDS) ------------
__global__ __launch_bounds__(256, 2) void gemm_pv_mfma(
    const unsigned short* __restrict__ Pg,
    const __hip_bfloat16* __restrict__ Vg,
    __hip_bfloat16* __restrict__ FEAT)
{
    __shared__ alignas(16) char lds[32768];
    char* ldsA = lds;
    char* ldsB = lds + 16384;
    int bid = blockIdx.x;
    int lb  = (bid & 7) * 256 + (bid >> 3);
    int bb  = lb >> 7;
    int tl  = lb & 127;
    int m0  = (tl >> 5) * 128;
    int n0  = (tl & 31) * 128;
    const unsigned short* Ag = Pg + (size_t)bb * S_ * S_ + (size_t)m0 * S_;
    const unsigned short* Bg = (const unsigned short*)Vg + (size_t)bb * S_ * D_ + n0;
    int t = threadIdx.x;
    int w = t >> 6, l = t & 63, q = l >> 4, l15 = l & 15;
    int wm = w >> 1, wn = w & 1;
    float4v acc[4][4] = {};
    for (int k0 = 0; k0 < S_; k0 += 64) {
        __syncthreads();
        stage_tile<256>(ldsA, Ag + k0, S_, t);
        stage_vt(ldsB, Bg + (size_t)k0 * D_, t);
        __syncthreads();
        #pragma unroll
        for (int kc = 0; kc < 2; ++kc) {
            int kB = kc * 64 + q * 16;
            short8v a[4], b[4];
            #pragma unroll
            for (int mt = 0; mt < 4; ++mt) a[mt] = frag_ld(ldsA, wm * 64 + mt * 16 + l15, kB);
            #pragma unroll
            for (int nt = 0; nt < 4; ++nt) b[nt] = frag_ld(ldsB, wn * 64 + nt * 16 + l15, kB);
            #pragma unroll
            for (int mt = 0; mt < 4; ++mt)
                #pragma unroll
                for (int nt = 0; nt < 4; ++nt)
                    acc[mt][nt] = __builtin_amdgcn_mfma_f32_16x16x32_bf16(
                        a[mt], b[nt], acc[mt][nt], 0, 0, 0);
        }
    }
    #pragma unroll
    for (int mt = 0; mt < 4; ++mt) {
        #pragma unroll
        for (int j = 0; j < 4; ++j) {
            int s = m0 + wm * 64 + mt * 16 + q * 4 + j;
            if (s >= S_) continue;
            int f  = bb * T_ + (s >> 6);
            int l6 = s & 63;
            #pragma unroll
            for (int nt = 0; nt < 4; ++nt) {
                int d = n0 + wn * 64 + nt * 16 + l15;
                int c = d >> 6, r = d & 63;
                int y  = ((l6 >> 3) << 3) + (r >> 3);
                int xx = ((l6 & 7) << 3) + (r & 7);
                FEAT[(((size_t)f * C_ + c) * H_ + y) * W_ + xx] =
                    __float2bfloat16(acc[mt][nt][j]);
            }
        }
    }
}

// ---------------------------------------------------------------------------
extern "C" void kernel_launch(void* const* d_in, const int* in_sizes, int n_in,
                              void* d_out, int out_size, void* d_ws, size_t ws_size,
                              hipStream_t stream)
{
    const float* x  = (const float*)d_in[0];
    const float* wq = (const float*)d_in[1];
    const float* bq = (const float*)d_in[2];
    const float* wk = (const float*)d_in[3];
    const float* bk = (const float*)d_in[4];
    const float* wv = (const float*)d_in[5];
    const float* bv = (const float*)d_in[6];
    const float* wc = (const float*)d_in[7];
    const float* bc = (const float*)d_in[8];
    float* out = (float*)d_out;

    __hip_bfloat16* Qb = (__hip_bfloat16*)d_ws;
    __hip_bfloat16* Kb = Qb + QKV_E;
    __hip_bfloat16* Vb = Kb + QKV_E;
    float* ATTN = (float*)(Vb + QKV_E);
    __hip_bfloat16* Wt_v = (__hip_bfloat16*)(ATTN + ATTN_E);
    __hip_bfloat16* Wt_c = Wt_v + 9 * 64 * 64;
    unsigned short* Pb   = (unsigned short*)Kb;   // aliases Kb (dead after qk)
    __hip_bfloat16* FEAT = Qb;                    // aliases Qb (dead after qk)

    prep_w2<<<288, 256, 0, stream>>>(wv, wc, Wt_v, Wt_c);

    conv_mfma6<true><<<dim3(16, NFR), 512, 0, stream>>>(
        x, Wt_v, bv, nullptr, Vb,
        wq, bq, wk, bk, (unsigned short*)Qb, (unsigned short*)Kb);
    gemm_qk_mfma<<<256, 512, 0, stream>>>(Qb, Kb, ATTN);
    softmax_rows<<<B_ * S_, 64, 0, stream>>>(ATTN, Pb);
    gemm_pv_mfma<<<2048, 256, 0, stream>>>(Pb, Vb, FEAT);
    conv_mfma6<false><<<dim3(16, NFR), 512, 0, stream>>>(
        FEAT, Wt_c, bc, x, out,
        nullptr, nullptr, nullptr, nullptr, nullptr, nullptr);
}